// Round 9
// baseline (661.504 us; speedup 1.0000x reference)
//
#include <hip/hip_runtime.h>

#define B_ 8
#define P_ 512
#define Q_ 64
#define A_ 16
#define H_ 128
#define H2_ 256
#define H10_ 1280
#define G_ 384

typedef float f32x4 __attribute__((ext_vector_type(4)));
typedef _Float16 half4_t __attribute__((ext_vector_type(4)));
typedef _Float16 half8_t __attribute__((ext_vector_type(8)));

__device__ __forceinline__ float fast_tanh(float x) {
  return 1.f - 2.f * __builtin_amdgcn_rcpf(1.f + __builtin_amdgcn_exp2f(2.88539008f * x));
}
__device__ __forceinline__ float fast_sigm(float x) {
  return __builtin_amdgcn_rcpf(1.f + __builtin_amdgcn_exp2f(-1.44269504f * x));
}

#define GRUBAR() asm volatile("s_waitcnt lgkmcnt(0)\n\ts_barrier" ::: "memory")

// ================= fused preprocessing mega-kernel =================
#define NB_PRE 6936

__device__ __forceinline__ void prep_frag_body(int idx, const float* __restrict__ W,
                                               _Float16* __restrict__ out, int KT, int HT, int N) {
  int total = KT * HT * 64 * 4;
  if (idx >= total) return;
  int e = idx & 3;
  int l = (idx >> 2) & 63;
  int rest = idx >> 8;
  int ht = rest % HT;
  int ks = rest / HT;
  int k = ks * 16 + ((l >> 4) << 2) + e;
  int n = ht * 16 + (l & 15);
  out[idx] = (_Float16)W[(size_t)k * N + n];
}

__device__ __forceinline__ void prep_frag32_body(int idx, const float* __restrict__ W,
                                                 _Float16* __restrict__ out, int KT, int HT, int N) {
  int total = KT * HT * 64 * 8;
  if (idx >= total) return;
  int e = idx & 7;
  int l = (idx >> 3) & 63;
  int rest = idx >> 9;
  int ht = rest % HT;
  int ks = rest / HT;
  int k = ks * 32 + ((l >> 4) << 3) + e;
  int n = ht * 16 + (l & 15);
  out[idx] = (_Float16)W[(size_t)k * N + n];
}

__global__ __launch_bounds__(256) void k_pre(
    const float* __restrict__ a1, const float* __restrict__ a2, const float* __restrict__ a3,
    const int* __restrict__ m1, const int* __restrict__ m2, const int* __restrict__ m3,
    const float* __restrict__ a_att_w, float* __restrict__ alters,
    const float* __restrict__ Wd, _Float16* __restrict__ wd_sw,
    const float* __restrict__ gWih_f, const float* __restrict__ gWih_b,
    _Float16* __restrict__ gih_sw,
    const float* __restrict__ gWhh_f, const float* __restrict__ gWhh_b,
    _Float16* __restrict__ whh_sw,
    const float* __restrict__ pas, const float* __restrict__ qry,
    _Float16* __restrict__ pas_h,
    const float* __restrict__ Wc1, const float* __restrict__ Wm, const float* __restrict__ Wb,
    _Float16* __restrict__ wpc_sw,
    float* __restrict__ qryT,
    const float* __restrict__ Wc2, float* __restrict__ q1T, float* __restrict__ pmqT,
    const float* __restrict__ wq, const float* __restrict__ vq, float* __restrict__ sjraw) {
  int bx = blockIdx.x;
  int tid = threadIdx.x;
  if (bx < 24) {
    int b = bx / 3, i = bx % 3;
    const float* x = (i == 0) ? a1 : (i == 1) ? a2 : a3;
    const int* mk = (i == 0) ? m1 : (i == 1) ? m2 : m3;
    __shared__ float sc[A_];
    __shared__ float sw[A_];
    if (tid < A_) {
      const float* row = x + ((size_t)(b * A_ + tid)) * H_;
      float acc = 0.f;
      for (int h = 0; h < H_; ++h) acc += row[h] * a_att_w[h];
      sc[tid] = (mk[b * A_ + tid] != 0) ? acc : -1e30f;
    }
    __syncthreads();
    if (tid == 0) {
      float mx = -1e30f;
      for (int a = 0; a < A_; ++a) mx = fmaxf(mx, sc[a]);
      float s = 0.f;
      for (int a = 0; a < A_; ++a) { float e = __expf(sc[a] - mx); sw[a] = e; s += e; }
      float inv = 1.f / s;
      for (int a = 0; a < A_; ++a) sw[a] *= inv;
    }
    __syncthreads();
    if (tid < H_) {
      float acc = 0.f;
      for (int a = 0; a < A_; ++a) acc += sw[a] * x[((size_t)(b * A_ + a)) * H_ + tid];
      alters[((size_t)(b * 3 + i)) * H_ + tid] = acc;
    }
    return;
  }
  bx -= 24;
  if (bx < 128) { prep_frag_body(bx * 256 + tid, Wd, wd_sw, 16, 8, H_); return; }
  bx -= 128;
  if (bx < 1920) { prep_frag_body(bx * 256 + tid, gWih_f, gih_sw, 80, 24, G_); return; }
  bx -= 1920;
  if (bx < 1920) {
    prep_frag_body(bx * 256 + tid, gWih_b, gih_sw + (size_t)80 * 24 * 64 * 4, 80, 24, G_);
    return;
  }
  bx -= 1920;
  if (bx < 192) { prep_frag32_body(bx * 256 + tid, gWhh_f, whh_sw, 4, 24, G_); return; }
  bx -= 192;
  if (bx < 192) {
    prep_frag32_body(bx * 256 + tid, gWhh_b, whh_sw + (size_t)4 * 24 * 64 * 8, 4, 24, G_);
    return;
  }
  bx -= 192;
  if (bx < 1024) {
    int idx = bx * 256 + tid;
    float4 v = *(const float4*)(pas + (size_t)idx * 4);
    half4_t h;
    h[0] = (_Float16)v.x; h[1] = (_Float16)v.y; h[2] = (_Float16)v.z; h[3] = (_Float16)v.w;
    *(half4_t*)(pas_h + (size_t)idx * 4) = h;
    return;
  }
  bx -= 1024;
  if (bx < 512) {
    int idx = bx * 256 + tid;
    int e = idx & 3;
    int l = (idx >> 2) & 63;
    int rest = idx >> 8;
    int ht = rest & 31;
    int ks = rest >> 5;
    int k = ks * 16 + ((l >> 4) << 2) + e;
    int n = ht * 16 + (l & 15);
    float v = (n < 128) ? Wc1[(size_t)k * 128 + n]
            : (n < 256) ? Wm[(size_t)k * 128 + (n - 128)]
                        : Wb[(size_t)k * 256 + (n - 256)];
    wpc_sw[idx] = (_Float16)v;
    return;
  }
  bx -= 512;
  if (bx < 512) {
    int idx = bx * 256 + tid;
    int q = idx & 63;
    int d = (idx >> 6) & 255;
    int b = idx >> 14;
    qryT[idx] = qry[((size_t)(b * Q_ + q)) * H2_ + d];
    return;
  }
  bx -= 512;
  if (bx < 256) {
    int idx = bx * 256 + tid;
    int h = idx & 127;
    int rest = idx >> 7;
    int q = rest & 63;
    int b = rest >> 6;
    const float* qr = qry + ((size_t)(b * Q_ + q)) * H2_;
    float a1v = 0.f, a2v = 0.f;
#pragma unroll 4
    for (int d = 0; d < H2_; ++d) {
      float qv = qr[d];
      a1v += qv * Wc2[(size_t)d * H_ + h];
      a2v += qv * Wm[(size_t)d * H_ + h];
    }
    q1T[((size_t)(b * H_ + h)) * Q_ + q] = a1v;
    pmqT[((size_t)(b * H_ + h)) * Q_ + q] = a2v;
    return;
  }
  bx -= 256;
  {
    int rs = tid >> 7;
    int h = tid & 127;
    int row = bx * 2 + rs;
    const float* qr = qry + (size_t)row * H2_;
    float acc = 0.f;
#pragma unroll 4
    for (int d = 0; d < H2_; ++d) acc += qr[d] * wq[(size_t)d * H_ + h];
    float v = fast_tanh(acc) * vq[h];
    for (int m = 32; m >= 1; m >>= 1) v += __shfl_xor(v, m);
    __shared__ float par[2][2];
    if ((h & 63) == 0) par[rs][h >> 6] = v;
    __syncthreads();
    if (h == 0) sjraw[row] = par[rs][0] + par[rs][1];
  }
}

// ================= sc_d (MFMA) + rq + pas-side MFMA gemm =================
__global__ __launch_bounds__(256) void k_scd_rq(
    const float* __restrict__ pas, const float* __restrict__ qry,
    const _Float16* __restrict__ wd_sw, const float* __restrict__ vd,
    float* __restrict__ scd,
    const float* __restrict__ sjraw, const int* __restrict__ qmask,
    const float* __restrict__ wp2, float* __restrict__ rqw2,
    const _Float16* __restrict__ pas_h, const _Float16* __restrict__ wpc_sw,
    float* __restrict__ p1, float* __restrict__ pmp, float* __restrict__ pasWb) {
  int bx0 = blockIdx.x;
  int tid = threadIdx.x;
  if (bx0 < B_ * Q_ * 8) {
    int pt = bx0 & 7;
    int rem = bx0 >> 3;
    int q = rem & (Q_ - 1);
    int b = rem >> 6;
    int w = tid >> 6, l = tid & 63;
    __shared__ __align__(16) float qs[H2_];
    __shared__ float vds[H_];
    if (tid < H2_) qs[tid] = qry[((size_t)(b * Q_ + q)) * H2_ + tid];
    if (tid < H_) vds[tid] = vd[tid];
    __syncthreads();
    int arow = pt * 64 + w * 16 + (l & 15);
    const float* prow = pas + ((size_t)(b * P_) + arow) * H2_;
    int ko = (l >> 4) << 2;
    f32x4 acc[8] = {};
#pragma unroll
    for (int ks = 0; ks < 16; ++ks) {
      int j0 = ks * 16 + ko;
      float4 pa = *(const float4*)(prow + j0);
      float4 qa = *(const float4*)(qs + j0);
      half4_t a;
      a[0] = (_Float16)(pa.x * qa.x);
      a[1] = (_Float16)(pa.y * qa.y);
      a[2] = (_Float16)(pa.z * qa.z);
      a[3] = (_Float16)(pa.w * qa.w);
      const _Float16* bb = wd_sw + (((size_t)(ks * 8) * 64) + l) * 4;
#pragma unroll
      for (int ht = 0; ht < 8; ++ht) {
        half4_t bf = *(const half4_t*)(bb + (size_t)ht * 64 * 4);
        acc[ht] = __builtin_amdgcn_mfma_f32_16x16x16f16(a, bf, acc[ht], 0, 0, 0);
      }
    }
    float part[4] = {0.f, 0.f, 0.f, 0.f};
#pragma unroll
    for (int ht = 0; ht < 8; ++ht) {
      float v = vds[ht * 16 + (l & 15)];
#pragma unroll
      for (int j = 0; j < 4; ++j) part[j] += v * fast_tanh(acc[ht][j]);
    }
#pragma unroll
    for (int j = 0; j < 4; ++j) {
      float s = part[j];
      s += __shfl_xor(s, 1);
      s += __shfl_xor(s, 2);
      s += __shfl_xor(s, 4);
      s += __shfl_xor(s, 8);
      part[j] = s;
    }
    if ((l & 15) == 0) {
      int pr = pt * 64 + w * 16 + ((l >> 4) << 2);
#pragma unroll
      for (int j = 0; j < 4; ++j)
        scd[((size_t)b * P_ + pr + j) * Q_ + q] = part[j];
    }
    return;
  }
  if (bx0 < B_ * Q_ * 8 + B_) {
    int b = bx0 - B_ * Q_ * 8;
    int t = tid;
    __shared__ float sj[Q_];
    __shared__ float rql[H2_];
    if (t < Q_) {
      float s = (qmask[b * Q_ + t] != 0) ? sjraw[b * Q_ + t] : -1e30f;
      float mx = s;
      for (int m = 32; m >= 1; m >>= 1) mx = fmaxf(mx, __shfl_xor(mx, m));
      float e = __expf(s - mx);
      float sum = e;
      for (int m = 32; m >= 1; m >>= 1) sum += __shfl_xor(sum, m);
      sj[t] = e / sum;
    }
    __syncthreads();
    {
      float acc = 0.f;
      const float* qcol = qry + (size_t)b * Q_ * H2_ + t;
#pragma unroll 8
      for (int q = 0; q < Q_; ++q) acc += sj[q] * qcol[(size_t)q * H2_];
      rql[t] = acc;
    }
    __syncthreads();
    if (t < H_) {
      float acc = 0.f;
#pragma unroll 4
      for (int d = 0; d < H2_; ++d) acc += rql[d] * wp2[(size_t)d * H_ + t];
      rqw2[b * H_ + t] = acc;
    }
    return;
  }
  {
    int bx2 = bx0 - (B_ * Q_ * 8 + B_);
    int rt = bx2 >> 1, nh = bx2 & 1;
    int w = tid >> 6, l = tid & 63;
    int p0 = rt * 64 + w * 16;
    const _Float16* arow = pas_h + ((size_t)(p0 + (l & 15))) * H2_ + ((l >> 4) << 2);
    const _Float16* bbase = wpc_sw + (size_t)l * 4;
    f32x4 acc[16] = {};
    for (int ks = 0; ks < 16; ++ks) {
      half4_t a = *(const half4_t*)(arow + ks * 16);
      const _Float16* bkt = bbase + ((size_t)(ks * 32 + nh * 16)) * 64 * 4;
#pragma unroll
      for (int ht = 0; ht < 16; ++ht) {
        half4_t bf = *(const half4_t*)(bkt + (size_t)ht * 64 * 4);
        acc[ht] = __builtin_amdgcn_mfma_f32_16x16x16f16(a, bf, acc[ht], 0, 0, 0);
      }
    }
    int r0 = p0 + ((l >> 4) << 2);
#pragma unroll
    for (int ht = 0; ht < 16; ++ht) {
      int col = (nh * 16 + ht) * 16 + (l & 15);
#pragma unroll
      for (int j = 0; j < 4; ++j) {
        float v = acc[ht][j];
        size_t row = r0 + j;
        if (col < 128) p1[row * H_ + col] = v;
        else if (col < 256) pmp[row * H_ + (col - 128)] = v;
        else pasWb[row * H2_ + (col - 256)] = v;
      }
    }
  }
}

// ---------------- k_attend v3: 2 p-rows per block, q-side loads amortized ----------------
__global__ __launch_bounds__(256) void k_attend(
    const float* __restrict__ pas, const float* __restrict__ qry,
    const float* __restrict__ p1, const float* __restrict__ pmp,
    const float* __restrict__ q1T, const float* __restrict__ pmqT,
    const float* __restrict__ qryT,
    const float* __restrict__ pasWb, const float* __restrict__ scd,
    const float* __restrict__ vc, const float* __restrict__ vm,
    const int* __restrict__ qmask, _Float16* __restrict__ agg_h) {
  int bx = blockIdx.x;
  int b = bx >> 8, p0 = (bx & 255) * 2;
  int tid = threadIdx.x;
  __shared__ float p1s[2][H_], pmps[2][H_];
  __shared__ float pbs[2][H2_];
  __shared__ float sscd[2][Q_];
  __shared__ float ps[2][3][4][Q_];
  __shared__ float asw[2][4][Q_];
  size_t rowp = (size_t)b * P_ + p0;
  if (tid < 2 * H_) {
    int pp = tid >> 7, h = tid & 127;
    p1s[pp][h] = p1[(rowp + pp) * H_ + h];
    pmps[pp][h] = pmp[(rowp + pp) * H_ + h];
  }
  {
    int pp = tid >> 7, d2 = (tid & 127) * 2;
    pbs[pp][d2] = pasWb[(rowp + pp) * H2_ + d2];
    pbs[pp][d2 + 1] = pasWb[(rowp + pp) * H2_ + d2 + 1];
  }
  if (tid < 2 * Q_) sscd[tid >> 6][tid & 63] = scd[(rowp + (tid >> 6)) * Q_ + (tid & 63)];
  __syncthreads();
  {
    int q = tid & 63, part = tid >> 6;
    const float* q1b = q1T + (size_t)b * H_ * Q_;
    const float* pmqb = pmqT + (size_t)b * H_ * Q_;
    const float* qTb = qryT + (size_t)b * H2_ * Q_;
    float sc0 = 0.f, sc1 = 0.f, sm0 = 0.f, sm1 = 0.f, sb0 = 0.f, sb1 = 0.f;
    int h0 = part * 32;
#pragma unroll 4
    for (int i = 0; i < 32; ++i) {
      int h = h0 + i;
      float q1v = q1b[h * Q_ + q];
      float pmqv = pmqb[h * Q_ + q];
      float vcv = vc[h], vmv = vm[h];
      sc0 += fast_tanh(p1s[0][h] + q1v) * vcv;
      sc1 += fast_tanh(p1s[1][h] + q1v) * vcv;
      sm0 += fast_tanh(pmqv - pmps[0][h]) * vmv;
      sm1 += fast_tanh(pmqv - pmps[1][h]) * vmv;
    }
    int d0 = part * 64;
#pragma unroll 4
    for (int i = 0; i < 64; ++i) {
      int d = d0 + i;
      float qv = qTb[d * Q_ + q];
      sb0 += pbs[0][d] * qv;
      sb1 += pbs[1][d] * qv;
    }
    ps[0][0][part][q] = sc0;
    ps[1][0][part][q] = sc1;
    ps[0][1][part][q] = sb0;
    ps[1][1][part][q] = sb1;
    ps[0][2][part][q] = sm0;
    ps[1][2][part][q] = sm1;
  }
  __syncthreads();
  {
    int wv = tid >> 6, lane = tid & 63;
    int msk = (qmask[b * Q_ + lane] != 0);
#pragma unroll
    for (int pp = 0; pp < 2; ++pp) {
      float s;
      if (wv == 2) s = sscd[pp][lane];
      else {
        int arr = (wv == 3) ? 2 : wv;
        s = (ps[pp][arr][0][lane] + ps[pp][arr][1][lane]) +
            (ps[pp][arr][2][lane] + ps[pp][arr][3][lane]);
      }
      s = msk ? s : -1e30f;
      float mx = s;
      for (int m = 32; m >= 1; m >>= 1) mx = fmaxf(mx, __shfl_xor(mx, m));
      float e = __expf(s - mx);
      float sum = e;
      for (int m = 32; m >= 1; m >>= 1) sum += __shfl_xor(sum, m);
      asw[pp][wv][lane] = e / sum;
    }
  }
  __syncthreads();
  {
    int d = tid;
    const float* qcol = qry + (size_t)b * Q_ * H2_ + d;
    float o00 = 0.f, o01 = 0.f, o02 = 0.f, o03 = 0.f;
    float o10 = 0.f, o11 = 0.f, o12 = 0.f, o13 = 0.f;
#pragma unroll 8
    for (int q2 = 0; q2 < Q_; ++q2) {
      float qv = qcol[(size_t)q2 * H2_];
      o00 += asw[0][0][q2] * qv;
      o01 += asw[0][1][q2] * qv;
      o02 += asw[0][2][q2] * qv;
      o03 += asw[0][3][q2] * qv;
      o10 += asw[1][0][q2] * qv;
      o11 += asw[1][1][q2] * qv;
      o12 += asw[1][2][q2] * qv;
      o13 += asw[1][3][q2] * qv;
    }
    _Float16* arow0 = agg_h + rowp * H10_;
    arow0[d] = (_Float16)pas[rowp * H2_ + d];
    arow0[256 + d] = (_Float16)o00;
    arow0[512 + d] = (_Float16)o01;
    arow0[768 + d] = (_Float16)o02;
    arow0[1024 + d] = (_Float16)o03;
    _Float16* arow1 = agg_h + (rowp + 1) * H10_;
    arow1[d] = (_Float16)pas[(rowp + 1) * H2_ + d];
    arow1[256 + d] = (_Float16)o10;
    arow1[512 + d] = (_Float16)o11;
    arow1[768 + d] = (_Float16)o12;
    arow1[1024 + d] = (_Float16)o13;
  }
}

// ---------------- gi = agg_in @ gWih + gbih (both dirs), f16 MFMA ----------------
__global__ __launch_bounds__(256) void k_gi(
    const _Float16* __restrict__ agg_h, const _Float16* __restrict__ gih_sw,
    const float* __restrict__ gbih_f, const float* __restrict__ gbih_b,
    float* __restrict__ gi_f, float* __restrict__ gi_b) {
  int dir = blockIdx.y;
  const float* gbih = dir ? gbih_b : gbih_f;
  float* gi = dir ? gi_b : gi_f;
  int tid = threadIdx.x;
  int w = tid >> 6, l = tid & 63;
  int p0 = blockIdx.x * 64 + w * 16;
  const _Float16* arow = agg_h + ((size_t)(p0 + (l & 15))) * H10_ + ((l >> 4) << 2);
  const _Float16* bbase = gih_sw + (size_t)dir * 80 * 24 * 64 * 4 + (size_t)l * 4;
  f32x4 acc[24] = {};
  for (int ks = 0; ks < 80; ++ks) {
    half4_t a = *(const half4_t*)(arow + ks * 16);
    const _Float16* bkt = bbase + (size_t)ks * 24 * 64 * 4;
#pragma unroll
    for (int ht = 0; ht < 24; ++ht) {
      half4_t bf = *(const half4_t*)(bkt + (size_t)ht * 64 * 4);
      acc[ht] = __builtin_amdgcn_mfma_f32_16x16x16f16(a, bf, acc[ht], 0, 0, 0);
    }
  }
  int r0 = p0 + ((l >> 4) << 2);
#pragma unroll
  for (int ht = 0; ht < 24; ++ht) {
    int col = ht * 16 + (l & 15);
    float bias = gbih[col];
#pragma unroll
    for (int j = 0; j < 4; ++j)
      gi[((size_t)(r0 + j)) * G_ + col] = acc[ht][j] + bias;
  }
}

// ---------------- GRU scan v8: 4 waves (1/SIMD), 2 col-tiles per gate per wave ----------------
// wave w owns cols [w*32, w*32+32); 24 MFMA/step (6 chains x 4 links);
// Bf = 96 VGPR; 1 raw barrier/step; 2-deep gi prefetch for 2 j's.
__global__ __attribute__((amdgpu_waves_per_eu(1, 1))) __launch_bounds__(256) void k_gru(
    const float* __restrict__ gi_f, const float* __restrict__ gi_b,
    const _Float16* __restrict__ whh_sw,
    const float* __restrict__ bhh_f, const float* __restrict__ bhh_b,
    float* __restrict__ agg) {
  int dir = blockIdx.x >> 3;
  int bb = blockIdx.x & 7;
  const float* gi = dir ? gi_b : gi_f;
  const float* bhh = dir ? bhh_b : bhh_f;
  int tid = threadIdx.x;
  int w = tid >> 6, l = tid & 63;
  int j0 = w * 32 + (l & 15);
  int j1 = j0 + 16;
  half8_t Bf[3][2][4];
  {
    const _Float16* wb = whh_sw + (size_t)dir * 4 * 24 * 64 * 8;
#pragma unroll
    for (int g = 0; g < 3; ++g)
#pragma unroll
      for (int cc = 0; cc < 2; ++cc) {
        int ct = g * 8 + w * 2 + cc;
#pragma unroll
        for (int ks = 0; ks < 4; ++ks)
          Bf[g][cc][ks] = *(const half8_t*)(wb + (((size_t)(ks * 24 + ct)) * 64 + l) * 8);
      }
  }
  float bhr0 = bhh[j0], bhz0 = bhh[128 + j0], bhn0 = bhh[256 + j0];
  float bhr1 = bhh[j1], bhz1 = bhh[128 + j1], bhn1 = bhh[256 + j1];
  __shared__ __align__(16) _Float16 hsbuf[2][H_];
  if (tid < H_) hsbuf[0][tid] = (_Float16)0.f;
  float hprev0 = 0.f, hprev1 = 0.f;
  int p = dir ? (P_ - 1) : 0;
  int dp = dir ? -1 : 1;
  size_t gbase = (size_t)bb * P_;
  float g0[6], g1[6];
  {
    size_t r0 = (gbase + p) * G_;
    g0[0] = gi[r0 + j0]; g0[1] = gi[r0 + 128 + j0]; g0[2] = gi[r0 + 256 + j0];
    g0[3] = gi[r0 + j1]; g0[4] = gi[r0 + 128 + j1]; g0[5] = gi[r0 + 256 + j1];
    size_t r1 = (gbase + p + dp) * G_;
    g1[0] = gi[r1 + j0]; g1[1] = gi[r1 + 128 + j0]; g1[2] = gi[r1 + 256 + j0];
    g1[3] = gi[r1 + j1]; g1[4] = gi[r1 + 128 + j1]; g1[5] = gi[r1 + 256 + j1];
  }
  GRUBAR();
  int cur = 0;
  int ao = (l >> 4) << 3;
  for (int t = 0; t < P_; ++t) {
    float g2[6] = {};
    if (t + 2 < P_) {
      size_t r2 = (gbase + p + 2 * dp) * G_;
      g2[0] = gi[r2 + j0]; g2[1] = gi[r2 + 128 + j0]; g2[2] = gi[r2 + 256 + j0];
      g2[3] = gi[r2 + j1]; g2[4] = gi[r2 + 128 + j1]; g2[5] = gi[r2 + 256 + j1];
    }
    const _Float16* hb = hsbuf[cur];
    half8_t ha[4];
#pragma unroll
    for (int ks = 0; ks < 4; ++ks) ha[ks] = *(const half8_t*)(hb + ks * 32 + ao);
    f32x4 ar0 = {}, ar1 = {}, az0 = {}, az1 = {}, an0 = {}, an1 = {};
#pragma unroll
    for (int ks = 0; ks < 4; ++ks) {
      ar0 = __builtin_amdgcn_mfma_f32_16x16x32_f16(ha[ks], Bf[0][0][ks], ar0, 0, 0, 0);
      az0 = __builtin_amdgcn_mfma_f32_16x16x32_f16(ha[ks], Bf[1][0][ks], az0, 0, 0, 0);
      an0 = __builtin_amdgcn_mfma_f32_16x16x32_f16(ha[ks], Bf[2][0][ks], an0, 0, 0, 0);
      ar1 = __builtin_amdgcn_mfma_f32_16x16x32_f16(ha[ks], Bf[0][1][ks], ar1, 0, 0, 0);
      az1 = __builtin_amdgcn_mfma_f32_16x16x32_f16(ha[ks], Bf[1][1][ks], az1, 0, 0, 0);
      an1 = __builtin_amdgcn_mfma_f32_16x16x32_f16(ha[ks], Bf[2][1][ks], an1, 0, 0, 0);
    }
    float r0v = fast_sigm(g0[0] + ar0[0] + bhr0);
    float z0v = fast_sigm(g0[1] + az0[0] + bhz0);
    float n0v = fast_tanh(g0[2] + r0v * (an0[0] + bhn0));
    float h0v = (1.f - z0v) * n0v + z0v * hprev0;
    float r1v = fast_sigm(g0[3] + ar1[0] + bhr1);
    float z1v = fast_sigm(g0[4] + az1[0] + bhz1);
    float n1v = fast_tanh(g0[5] + r1v * (an1[0] + bhn1));
    float h1v = (1.f - z1v) * n1v + z1v * hprev1;
    hprev0 = h0v;
    hprev1 = h1v;
    if (l < 16) {
      hsbuf[cur ^ 1][j0] = (_Float16)h0v;
      hsbuf[cur ^ 1][j1] = (_Float16)h1v;
      float* arow = agg + (size_t)(gbase + p) * H2_ + dir * H_;
      arow[j0] = h0v;
      arow[j1] = h1v;
    }
    GRUBAR();
    cur ^= 1;
#pragma unroll
    for (int i = 0; i < 6; ++i) { g0[i] = g1[i]; g1[i] = g2[i]; }
    p += dp;
  }
}

// ---------------- sp raw scores v2: 8 p-rows per block ----------------
__global__ __launch_bounds__(128) void k_spscore(
    const float* __restrict__ agg, const float* __restrict__ wp1,
    const float* __restrict__ rqw2, const float* __restrict__ vp,
    float* __restrict__ spraw) {
  int bx = blockIdx.x;
  int b = bx >> 6, p0 = (bx & 63) * 8;
  int h = threadIdx.x;
  const float* ar = agg + ((size_t)b * P_ + p0) * H2_;
  float base = rqw2[b * H_ + h];
  float acc[8];
#pragma unroll
  for (int r = 0; r < 8; ++r) acc[r] = base;
#pragma unroll 4
  for (int d = 0; d < H2_; ++d) {
    float wv = wp1[(size_t)d * H_ + h];
#pragma unroll
    for (int r = 0; r < 8; ++r) acc[r] += ar[(size_t)r * H2_ + d] * wv;
  }
  __shared__ float par[8][2];
  float vph = vp[h];
#pragma unroll
  for (int r = 0; r < 8; ++r) {
    float v = fast_tanh(acc[r]) * vph;
    for (int m = 32; m >= 1; m >>= 1) v += __shfl_xor(v, m);
    if ((h & 63) == 0) par[r][h >> 6] = v;
  }
  __syncthreads();
  if (h < 8) spraw[(size_t)b * P_ + p0 + h] = par[h][0] + par[h][1];
}

// ---------------- final head ----------------
__global__ __launch_bounds__(256) void k_final(
    const float* __restrict__ spraw, const int* __restrict__ pmask,
    const float* __restrict__ agg, const float* __restrict__ predict_w,
    const float* __restrict__ alters, float* __restrict__ out) {
  int b = blockIdx.x;
  int t = threadIdx.x;
  __shared__ float sp[P_];
  __shared__ float red[4];
  __shared__ float rpr[H2_];
  __shared__ float rpl[H_];
  __shared__ float lg[3];
  float s0 = (pmask[b * P_ + t] != 0) ? spraw[b * P_ + t] : -1e30f;
  float s1 = (pmask[b * P_ + 256 + t] != 0) ? spraw[b * P_ + 256 + t] : -1e30f;
  float mx = fmaxf(s0, s1);
  for (int m = 32; m >= 1; m >>= 1) mx = fmaxf(mx, __shfl_xor(mx, m));
  if ((t & 63) == 0) red[t >> 6] = mx;
  __syncthreads();
  mx = fmaxf(fmaxf(red[0], red[1]), fmaxf(red[2], red[3]));
  float e0 = __expf(s0 - mx), e1 = __expf(s1 - mx);
  float ss = e0 + e1;
  for (int m = 32; m >= 1; m >>= 1) ss += __shfl_xor(ss, m);
  __syncthreads();
  if ((t & 63) == 0) red[t >> 6] = ss;
  __syncthreads();
  float tot = red[0] + red[1] + red[2] + red[3];
  float inv = 1.f / tot;
  sp[t] = e0 * inv;
  sp[256 + t] = e1 * inv;
  __syncthreads();
  {
    float acc = 0.f;
    const float* acol = agg + (size_t)b * P_ * H2_ + t;
#pragma unroll 8
    for (int p = 0; p < P_; ++p) acc += sp[p] * acol[(size_t)p * H2_];
    rpr[t] = acc;
  }
  __syncthreads();
  if (t < H_) {
    float acc = 0.f;
#pragma unroll 4
    for (int d = 0; d < H2_; ++d) acc += rpr[d] * predict_w[(size_t)d * H_ + t];
    rpl[t] = (acc > 0.f) ? acc : 0.01f * acc;
  }
  __syncthreads();
  if (t < 3) {
    float acc = 0.f;
    const float* al = alters + ((size_t)(b * 3 + t)) * H_;
    for (int h = 0; h < H_; ++h) acc += al[h] * rpl[h];
    lg[t] = acc;
  }
  __syncthreads();
  if (t == 0) {
    float m3 = fmaxf(lg[0], fmaxf(lg[1], lg[2]));
    float x0 = __expf(lg[0] - m3), x1 = __expf(lg[1] - m3), x2 = __expf(lg[2] - m3);
    float is = 1.f / (x0 + x1 + x2);
    out[b * 3 + 0] = x0 * is;
    out[b * 3 + 1] = x1 * is;
    out[b * 3 + 2] = x2 * is;
  }
}

extern "C" void kernel_launch(void* const* d_in, const int* in_sizes, int n_in,
                              void* d_out, int out_size, void* d_ws, size_t ws_size,
                              hipStream_t stream) {
  (void)in_sizes; (void)n_in; (void)out_size; (void)ws_size;
  const float* pas = (const float*)d_in[0];
  const float* qry = (const float*)d_in[1];
  const float* alt1 = (const float*)d_in[2];
  const float* alt2 = (const float*)d_in[3];
  const float* alt3 = (const float*)d_in[4];
  const float* a_att_w = (const float*)d_in[5];
  const float* Wc1 = (const float*)d_in[6];
  const float* Wc2 = (const float*)d_in[7];
  const float* vc = (const float*)d_in[8];
  const float* Wb = (const float*)d_in[9];
  const float* Wd = (const float*)d_in[10];
  const float* vd = (const float*)d_in[11];
  const float* Wm = (const float*)d_in[12];
  const float* vm = (const float*)d_in[13];
  const float* wq = (const float*)d_in[14];
  const float* vq = (const float*)d_in[15];
  const float* wp1 = (const float*)d_in[16];
  const float* wp2 = (const float*)d_in[17];
  const float* vp = (const float*)d_in[18];
  const float* predict_w = (const float*)d_in[19];
  const float* gWih_f = (const float*)d_in[20];
  const float* gWhh_f = (const float*)d_in[21];
  const float* gbih_f = (const float*)d_in[22];
  const float* gbhh_f = (const float*)d_in[23];
  const float* gWih_b = (const float*)d_in[24];
  const float* gWhh_b = (const float*)d_in[25];
  const float* gbih_b = (const float*)d_in[26];
  const float* gbhh_b = (const float*)d_in[27];
  const int* pmask = (const int*)d_in[28];
  const int* qmask = (const int*)d_in[29];
  const int* m1 = (const int*)d_in[30];
  const int* m2 = (const int*)d_in[31];
  const int* m3 = (const int*)d_in[32];
  float* out = (float*)d_out;

  char* ws = (char*)d_ws;
  size_t off = 0;
  auto alloc_f = [&](size_t n) {
    float* ptr = (float*)(ws + off);
    off += n * 4;
    off = (off + 255) & ~(size_t)255;
    return ptr;
  };
  float* alters = alloc_f((size_t)B_ * 3 * H_);
  float* p1 = alloc_f((size_t)B_ * P_ * H_);
  float* pmp = alloc_f((size_t)B_ * P_ * H_);
  float* pasWb = alloc_f((size_t)B_ * P_ * H2_);
  float* scd = alloc_f((size_t)B_ * P_ * Q_);
  float* gi_f = alloc_f((size_t)B_ * P_ * G_);
  float* gi_b = alloc_f((size_t)B_ * P_ * G_);
  float* agg = alloc_f((size_t)B_ * P_ * H2_);
  float* sjraw = alloc_f((size_t)B_ * Q_);
  float* rqw2 = alloc_f((size_t)B_ * H_);
  float* spraw = alloc_f((size_t)B_ * P_);
  float* q1T = alloc_f((size_t)B_ * H_ * Q_);
  float* pmqT = alloc_f((size_t)B_ * H_ * Q_);
  float* qryT = alloc_f((size_t)B_ * H2_ * Q_);
  auto alloc_h = [&](size_t n) {
    _Float16* ptr = (_Float16*)(ws + off);
    off += n * 2;
    off = (off + 255) & ~(size_t)255;
    return ptr;
  };
  _Float16* wd_sw = alloc_h((size_t)16 * 8 * 64 * 4);
  _Float16* gih_sw = alloc_h((size_t)2 * 80 * 24 * 64 * 4);
  _Float16* agg_h = alloc_h((size_t)B_ * P_ * H10_);
  _Float16* whh_sw = alloc_h((size_t)2 * 4 * 24 * 64 * 8);
  _Float16* pas_h = alloc_h((size_t)B_ * P_ * H2_);
  _Float16* wpc_sw = alloc_h((size_t)16 * 32 * 64 * 4);

  k_pre<<<NB_PRE, 256, 0, stream>>>(
      alt1, alt2, alt3, m1, m2, m3, a_att_w, alters,
      Wd, wd_sw, gWih_f, gWih_b, gih_sw, gWhh_f, gWhh_b, whh_sw,
      pas, qry, pas_h, Wc1, Wm, Wb, wpc_sw, qryT, Wc2, q1T, pmqT, wq, vq, sjraw);
  k_scd_rq<<<B_ * Q_ * 8 + B_ + 128, 256, 0, stream>>>(
      pas, qry, wd_sw, vd, scd, sjraw, qmask, wp2, rqw2,
      pas_h, wpc_sw, p1, pmp, pasWb);
  k_attend<<<B_ * P_ / 2, 256, 0, stream>>>(
      pas, qry, p1, pmp, q1T, pmqT, qryT, pasWb, scd, vc, vm, qmask, agg_h);
  k_gi<<<dim3(64, 2), 256, 0, stream>>>(agg_h, gih_sw, gbih_f, gbih_b, gi_f, gi_b);
  k_gru<<<16, 256, 0, stream>>>(gi_f, gi_b, whh_sw, gbhh_f, gbhh_b, agg);
  k_spscore<<<B_ * P_ / 8, 128, 0, stream>>>(agg, wp1, rqw2, vp, spraw);
  k_final<<<B_, 256, 0, stream>>>(spraw, pmask, agg, predict_w, alters, out);
}

// Round 10
// 549.585 us; speedup vs baseline: 1.2036x; 1.2036x over previous
//
#include <hip/hip_runtime.h>

#define B_ 8
#define P_ 512
#define Q_ 64
#define A_ 16
#define H_ 128
#define H2_ 256
#define H10_ 1280
#define G_ 384

typedef float f32x4 __attribute__((ext_vector_type(4)));
typedef _Float16 half4_t __attribute__((ext_vector_type(4)));
typedef _Float16 half8_t __attribute__((ext_vector_type(8)));

__device__ __forceinline__ float fast_tanh(float x) {
  return 1.f - 2.f * __builtin_amdgcn_rcpf(1.f + __builtin_amdgcn_exp2f(2.88539008f * x));
}
__device__ __forceinline__ float fast_sigm(float x) {
  return __builtin_amdgcn_rcpf(1.f + __builtin_amdgcn_exp2f(-1.44269504f * x));
}

#define GRUBAR() asm volatile("s_waitcnt lgkmcnt(0)\n\ts_barrier" ::: "memory")

// ================= fused preprocessing mega-kernel (vectorized) =================
// blockIdx ranges (256 thr):
//  [0,24)        alters pooling
//  [24,56)       prep_frag4 Wd        (8192 thr)
//  [56,536)      prep_frag4 gWih_f    (122880)
//  [536,1016)    prep_frag4 gWih_b
//  [1016,1040)   prep_frag32_8 gWhh_f (6144)
//  [1040,1064)   prep_frag32_8 gWhh_b
//  [1064,1576)   pas -> pas_h (8/thr)
//  [1576,1704)   wpc4 = [Wc1|Wm|Wb] pack (32768)
//  [1704,1832)   qryT4 transpose (32768)
//  [1832,2088)   q-side gemm -> q1T, pmqT
//  [2088,2344)   qscore (2 rows/block)
#define NB_PRE 2344

// 4 consecutive k per thread -> half4 write
__device__ __forceinline__ void prep_frag4_body(int idx, const float* __restrict__ W,
                                                _Float16* __restrict__ out, int KT, int HT, int N) {
  int total = KT * HT * 64;
  if (idx >= total) return;
  int l = idx & 63;
  int rest = idx >> 6;
  int ht = rest % HT;
  int ks = rest / HT;
  int k = ks * 16 + ((l >> 4) << 2);
  int n = ht * 16 + (l & 15);
  half4_t o;
#pragma unroll
  for (int e = 0; e < 4; ++e) o[e] = (_Float16)W[(size_t)(k + e) * N + n];
  *(half4_t*)(out + (size_t)idx * 4) = o;
}

// K=32 fragment: 8 consecutive k per thread -> half8 write
__device__ __forceinline__ void prep_frag32_8_body(int idx, const float* __restrict__ W,
                                                   _Float16* __restrict__ out, int KT, int HT, int N) {
  int total = KT * HT * 64;
  if (idx >= total) return;
  int l = idx & 63;
  int rest = idx >> 6;
  int ht = rest % HT;
  int ks = rest / HT;
  int k = ks * 32 + ((l >> 4) << 3);
  int n = ht * 16 + (l & 15);
  half8_t o;
#pragma unroll
  for (int e = 0; e < 8; ++e) o[e] = (_Float16)W[(size_t)(k + e) * N + n];
  *(half8_t*)(out + (size_t)idx * 8) = o;
}

__global__ __launch_bounds__(256) void k_pre(
    const float* __restrict__ a1, const float* __restrict__ a2, const float* __restrict__ a3,
    const int* __restrict__ m1, const int* __restrict__ m2, const int* __restrict__ m3,
    const float* __restrict__ a_att_w, float* __restrict__ alters,
    const float* __restrict__ Wd, _Float16* __restrict__ wd_sw,
    const float* __restrict__ gWih_f, const float* __restrict__ gWih_b,
    _Float16* __restrict__ gih_sw,
    const float* __restrict__ gWhh_f, const float* __restrict__ gWhh_b,
    _Float16* __restrict__ whh_sw,
    const float* __restrict__ pas, const float* __restrict__ qry,
    _Float16* __restrict__ pas_h,
    const float* __restrict__ Wc1, const float* __restrict__ Wm, const float* __restrict__ Wb,
    _Float16* __restrict__ wpc_sw,
    float* __restrict__ qryT,
    const float* __restrict__ Wc2, float* __restrict__ q1T, float* __restrict__ pmqT,
    const float* __restrict__ wq, const float* __restrict__ vq, float* __restrict__ sjraw) {
  int bx = blockIdx.x;
  int tid = threadIdx.x;
  if (bx < 24) {
    int b = bx / 3, i = bx % 3;
    const float* x = (i == 0) ? a1 : (i == 1) ? a2 : a3;
    const int* mk = (i == 0) ? m1 : (i == 1) ? m2 : m3;
    __shared__ float sc[A_];
    __shared__ float sw[A_];
    if (tid < A_) {
      const float* row = x + ((size_t)(b * A_ + tid)) * H_;
      float acc = 0.f;
      for (int h = 0; h < H_; ++h) acc += row[h] * a_att_w[h];
      sc[tid] = (mk[b * A_ + tid] != 0) ? acc : -1e30f;
    }
    __syncthreads();
    if (tid == 0) {
      float mx = -1e30f;
      for (int a = 0; a < A_; ++a) mx = fmaxf(mx, sc[a]);
      float s = 0.f;
      for (int a = 0; a < A_; ++a) { float e = __expf(sc[a] - mx); sw[a] = e; s += e; }
      float inv = 1.f / s;
      for (int a = 0; a < A_; ++a) sw[a] *= inv;
    }
    __syncthreads();
    if (tid < H_) {
      float acc = 0.f;
      for (int a = 0; a < A_; ++a) acc += sw[a] * x[((size_t)(b * A_ + a)) * H_ + tid];
      alters[((size_t)(b * 3 + i)) * H_ + tid] = acc;
    }
    return;
  }
  bx -= 24;
  if (bx < 32) { prep_frag4_body(bx * 256 + tid, Wd, wd_sw, 16, 8, H_); return; }
  bx -= 32;
  if (bx < 480) { prep_frag4_body(bx * 256 + tid, gWih_f, gih_sw, 80, 24, G_); return; }
  bx -= 480;
  if (bx < 480) {
    prep_frag4_body(bx * 256 + tid, gWih_b, gih_sw + (size_t)80 * 24 * 64 * 4, 80, 24, G_);
    return;
  }
  bx -= 480;
  if (bx < 24) { prep_frag32_8_body(bx * 256 + tid, gWhh_f, whh_sw, 4, 24, G_); return; }
  bx -= 24;
  if (bx < 24) {
    prep_frag32_8_body(bx * 256 + tid, gWhh_b, whh_sw + (size_t)4 * 24 * 64 * 8, 4, 24, G_);
    return;
  }
  bx -= 24;
  if (bx < 512) {
    // pas -> f16, 8 elems/thread
    int idx = bx * 256 + tid;
    float4 v0 = *(const float4*)(pas + (size_t)idx * 8);
    float4 v1 = *(const float4*)(pas + (size_t)idx * 8 + 4);
    half8_t h;
    h[0] = (_Float16)v0.x; h[1] = (_Float16)v0.y; h[2] = (_Float16)v0.z; h[3] = (_Float16)v0.w;
    h[4] = (_Float16)v1.x; h[5] = (_Float16)v1.y; h[6] = (_Float16)v1.z; h[7] = (_Float16)v1.w;
    *(half8_t*)(pas_h + (size_t)idx * 8) = h;
    return;
  }
  bx -= 512;
  if (bx < 128) {
    // Wpc fragment pack, 4 k per thread: combined cols [Wc1|Wm|Wb], N=512, KT=16, HT=32
    int idx = bx * 256 + tid;
    int l = idx & 63;
    int rest = idx >> 6;
    int ht = rest & 31;
    int ks = rest >> 5;
    int k = ks * 16 + ((l >> 4) << 2);
    int n = ht * 16 + (l & 15);
    half4_t o;
#pragma unroll
    for (int e = 0; e < 4; ++e) {
      int kk = k + e;
      float v = (n < 128) ? Wc1[(size_t)kk * 128 + n]
              : (n < 256) ? Wm[(size_t)kk * 128 + (n - 128)]
                          : Wb[(size_t)kk * 256 + (n - 256)];
      o[e] = (_Float16)v;
    }
    *(half4_t*)(wpc_sw + (size_t)idx * 4) = o;
    return;
  }
  bx -= 128;
  if (bx < 128) {
    // qryT[b][d][q], 4 q per thread
    int idx = bx * 256 + tid;
    int q4 = idx & 15;
    int d = (idx >> 4) & 255;
    int b = idx >> 12;
    float4 o;
    o.x = qry[((size_t)(b * Q_ + q4 * 4 + 0)) * H2_ + d];
    o.y = qry[((size_t)(b * Q_ + q4 * 4 + 1)) * H2_ + d];
    o.z = qry[((size_t)(b * Q_ + q4 * 4 + 2)) * H2_ + d];
    o.w = qry[((size_t)(b * Q_ + q4 * 4 + 3)) * H2_ + d];
    *(float4*)(qryT + ((size_t)(b * H2_ + d)) * Q_ + q4 * 4) = o;
    return;
  }
  bx -= 128;
  if (bx < 256) {
    int idx = bx * 256 + tid;
    int h = idx & 127;
    int rest = idx >> 7;
    int q = rest & 63;
    int b = rest >> 6;
    const float* qr = qry + ((size_t)(b * Q_ + q)) * H2_;
    float a1v = 0.f, a2v = 0.f;
#pragma unroll 4
    for (int d = 0; d < H2_; ++d) {
      float qv = qr[d];
      a1v += qv * Wc2[(size_t)d * H_ + h];
      a2v += qv * Wm[(size_t)d * H_ + h];
    }
    q1T[((size_t)(b * H_ + h)) * Q_ + q] = a1v;
    pmqT[((size_t)(b * H_ + h)) * Q_ + q] = a2v;
    return;
  }
  bx -= 256;
  {
    int rs = tid >> 7;
    int h = tid & 127;
    int row = bx * 2 + rs;
    const float* qr = qry + (size_t)row * H2_;
    float acc = 0.f;
#pragma unroll 4
    for (int d = 0; d < H2_; ++d) acc += qr[d] * wq[(size_t)d * H_ + h];
    float v = fast_tanh(acc) * vq[h];
    for (int m = 32; m >= 1; m >>= 1) v += __shfl_xor(v, m);
    __shared__ float par[2][2];
    if ((h & 63) == 0) par[rs][h >> 6] = v;
    __syncthreads();
    if (h == 0) sjraw[row] = par[rs][0] + par[rs][1];
  }
}

// ================= sc_d v2 (8 q/block, LDS wd + pas_h regs) + rq + pas MFMA gemm =================
// blocks: [0,512) scd (b,pt,qg); [512,520) rq; [520,648) pas@[Wc1|Wm|Wb]
__global__ __launch_bounds__(256) void k_scd_rq(
    const float* __restrict__ qry,
    const _Float16* __restrict__ wd_sw, const float* __restrict__ vd,
    float* __restrict__ scd,
    const float* __restrict__ sjraw, const int* __restrict__ qmask,
    const float* __restrict__ wp2, float* __restrict__ rqw2,
    const _Float16* __restrict__ pas_h, const _Float16* __restrict__ wpc_sw,
    float* __restrict__ p1, float* __restrict__ pmp, float* __restrict__ pasWb) {
  __shared__ __align__(16) char smem[65536 + 8192 + 512];
  int bx0 = blockIdx.x;
  int tid = threadIdx.x;
  if (bx0 < 512) {
    int b = bx0 >> 6;
    int pt = (bx0 >> 3) & 7;
    int qg = bx0 & 7;
    _Float16* wlds = (_Float16*)smem;                       // 64KB: wd fragments
    float (*qs8)[H2_] = (float(*)[H2_])(smem + 65536);      // 8KB: 8 q-rows
    float* vds = (float*)(smem + 65536 + 8192);
    {
      const uint4* wsrc = (const uint4*)wd_sw;
      uint4* wdst = (uint4*)wlds;
#pragma unroll
      for (int i = 0; i < 16; ++i) wdst[tid + 256 * i] = wsrc[tid + 256 * i];
    }
#pragma unroll
    for (int qi = 0; qi < 8; ++qi)
      qs8[qi][tid] = qry[((size_t)(b * Q_ + qg * 8 + qi)) * H2_ + tid];
    if (tid < H_) vds[tid] = vd[tid];
    __syncthreads();
    int w = tid >> 6, l = tid & 63;
    int ko = (l >> 4) << 2;
    const _Float16* prow = pas_h + ((size_t)(b * P_) + pt * 64 + w * 16 + (l & 15)) * H2_ + ko;
    half4_t pah[16];
#pragma unroll
    for (int ks = 0; ks < 16; ++ks) pah[ks] = *(const half4_t*)(prow + ks * 16);
    for (int qi = 0; qi < 8; ++qi) {
      f32x4 acc[8] = {};
#pragma unroll
      for (int ks = 0; ks < 16; ++ks) {
        float4 qa = *(const float4*)(&qs8[qi][ks * 16 + ko]);
        half4_t a;
        a[0] = (_Float16)((float)pah[ks][0] * qa.x);
        a[1] = (_Float16)((float)pah[ks][1] * qa.y);
        a[2] = (_Float16)((float)pah[ks][2] * qa.z);
        a[3] = (_Float16)((float)pah[ks][3] * qa.w);
        const _Float16* bb = wlds + (((size_t)(ks * 8)) * 64 + l) * 4;
#pragma unroll
        for (int ht = 0; ht < 8; ++ht) {
          half4_t bf = *(const half4_t*)(bb + (size_t)ht * 64 * 4);
          acc[ht] = __builtin_amdgcn_mfma_f32_16x16x16f16(a, bf, acc[ht], 0, 0, 0);
        }
      }
      float part[4] = {0.f, 0.f, 0.f, 0.f};
#pragma unroll
      for (int ht = 0; ht < 8; ++ht) {
        float v = vds[ht * 16 + (l & 15)];
#pragma unroll
        for (int j = 0; j < 4; ++j) part[j] += v * fast_tanh(acc[ht][j]);
      }
#pragma unroll
      for (int j = 0; j < 4; ++j) {
        float s = part[j];
        s += __shfl_xor(s, 1);
        s += __shfl_xor(s, 2);
        s += __shfl_xor(s, 4);
        s += __shfl_xor(s, 8);
        part[j] = s;
      }
      if ((l & 15) == 0) {
        int pr = pt * 64 + w * 16 + ((l >> 4) << 2);
        int q = qg * 8 + qi;
#pragma unroll
        for (int j = 0; j < 4; ++j)
          scd[((size_t)b * P_ + pr + j) * Q_ + q] = part[j];
      }
    }
    return;
  }
  if (bx0 < 512 + B_) {
    // rq + rq@wp2
    int b = bx0 - 512;
    int t = tid;
    float* sj = (float*)smem;
    float* rql = (float*)(smem + Q_ * 4);
    if (t < Q_) {
      float s = (qmask[b * Q_ + t] != 0) ? sjraw[b * Q_ + t] : -1e30f;
      float mx = s;
      for (int m = 32; m >= 1; m >>= 1) mx = fmaxf(mx, __shfl_xor(mx, m));
      float e = __expf(s - mx);
      float sum = e;
      for (int m = 32; m >= 1; m >>= 1) sum += __shfl_xor(sum, m);
      sj[t] = e / sum;
    }
    __syncthreads();
    {
      float acc = 0.f;
      const float* qcol = qry + (size_t)b * Q_ * H2_ + t;
#pragma unroll 8
      for (int q = 0; q < Q_; ++q) acc += sj[q] * qcol[(size_t)q * H2_];
      rql[t] = acc;
    }
    __syncthreads();
    if (t < H_) {
      float acc = 0.f;
#pragma unroll 4
      for (int d = 0; d < H2_; ++d) acc += rql[d] * wp2[(size_t)d * H_ + t];
      rqw2[b * H_ + t] = acc;
    }
    return;
  }
  {
    // pas-side MFMA gemm: 128 blocks = 64 row-tiles x 2 N-halves
    int bx2 = bx0 - (512 + B_);
    int rt = bx2 >> 1, nh = bx2 & 1;
    int w = tid >> 6, l = tid & 63;
    int p0 = rt * 64 + w * 16;
    const _Float16* arow = pas_h + ((size_t)(p0 + (l & 15))) * H2_ + ((l >> 4) << 2);
    const _Float16* bbase = wpc_sw + (size_t)l * 4;
    f32x4 acc[16] = {};
    for (int ks = 0; ks < 16; ++ks) {
      half4_t a = *(const half4_t*)(arow + ks * 16);
      const _Float16* bkt = bbase + ((size_t)(ks * 32 + nh * 16)) * 64 * 4;
#pragma unroll
      for (int ht = 0; ht < 16; ++ht) {
        half4_t bf = *(const half4_t*)(bkt + (size_t)ht * 64 * 4);
        acc[ht] = __builtin_amdgcn_mfma_f32_16x16x16f16(a, bf, acc[ht], 0, 0, 0);
      }
    }
    int r0 = p0 + ((l >> 4) << 2);
#pragma unroll
    for (int ht = 0; ht < 16; ++ht) {
      int col = (nh * 16 + ht) * 16 + (l & 15);
#pragma unroll
      for (int j = 0; j < 4; ++j) {
        float v = acc[ht][j];
        size_t row = r0 + j;
        if (col < 128) p1[row * H_ + col] = v;
        else if (col < 256) pmp[row * H_ + (col - 128)] = v;
        else pasWb[row * H2_ + (col - 256)] = v;
      }
    }
  }
}

// ---------------- k_attend v3: 2 p-rows per block, coalesced q-side ----------------
__global__ __launch_bounds__(256) void k_attend(
    const float* __restrict__ pas, const float* __restrict__ qry,
    const float* __restrict__ p1, const float* __restrict__ pmp,
    const float* __restrict__ q1T, const float* __restrict__ pmqT,
    const float* __restrict__ qryT,
    const float* __restrict__ pasWb, const float* __restrict__ scd,
    const float* __restrict__ vc, const float* __restrict__ vm,
    const int* __restrict__ qmask, _Float16* __restrict__ agg_h) {
  int bx = blockIdx.x;
  int b = bx >> 8, p0 = (bx & 255) * 2;
  int tid = threadIdx.x;
  __shared__ float p1s[2][H_], pmps[2][H_];
  __shared__ float pbs[2][H2_];
  __shared__ float sscd[2][Q_];
  __shared__ float ps[2][3][4][Q_];
  __shared__ float asw[2][4][Q_];
  size_t rowp = (size_t)b * P_ + p0;
  if (tid < 2 * H_) {
    int pp = tid >> 7, h = tid & 127;
    p1s[pp][h] = p1[(rowp + pp) * H_ + h];
    pmps[pp][h] = pmp[(rowp + pp) * H_ + h];
  }
  {
    int pp = tid >> 7, d2 = (tid & 127) * 2;
    pbs[pp][d2] = pasWb[(rowp + pp) * H2_ + d2];
    pbs[pp][d2 + 1] = pasWb[(rowp + pp) * H2_ + d2 + 1];
  }
  if (tid < 2 * Q_) sscd[tid >> 6][tid & 63] = scd[(rowp + (tid >> 6)) * Q_ + (tid & 63)];
  __syncthreads();
  {
    int q = tid & 63, part = tid >> 6;
    const float* q1b = q1T + (size_t)b * H_ * Q_;
    const float* pmqb = pmqT + (size_t)b * H_ * Q_;
    const float* qTb = qryT + (size_t)b * H2_ * Q_;
    float sc0 = 0.f, sc1 = 0.f, sm0 = 0.f, sm1 = 0.f, sb0 = 0.f, sb1 = 0.f;
    int h0 = part * 32;
#pragma unroll 4
    for (int i = 0; i < 32; ++i) {
      int h = h0 + i;
      float q1v = q1b[h * Q_ + q];
      float pmqv = pmqb[h * Q_ + q];
      float vcv = vc[h], vmv = vm[h];
      sc0 += fast_tanh(p1s[0][h] + q1v) * vcv;
      sc1 += fast_tanh(p1s[1][h] + q1v) * vcv;
      sm0 += fast_tanh(pmqv - pmps[0][h]) * vmv;
      sm1 += fast_tanh(pmqv - pmps[1][h]) * vmv;
    }
    int d0 = part * 64;
#pragma unroll 4
    for (int i = 0; i < 64; ++i) {
      int d = d0 + i;
      float qv = qTb[d * Q_ + q];
      sb0 += pbs[0][d] * qv;
      sb1 += pbs[1][d] * qv;
    }
    ps[0][0][part][q] = sc0;
    ps[1][0][part][q] = sc1;
    ps[0][1][part][q] = sb0;
    ps[1][1][part][q] = sb1;
    ps[0][2][part][q] = sm0;
    ps[1][2][part][q] = sm1;
  }
  __syncthreads();
  {
    int wv = tid >> 6, lane = tid & 63;
    int msk = (qmask[b * Q_ + lane] != 0);
#pragma unroll
    for (int pp = 0; pp < 2; ++pp) {
      float s;
      if (wv == 2) s = sscd[pp][lane];
      else {
        int arr = (wv == 3) ? 2 : wv;
        s = (ps[pp][arr][0][lane] + ps[pp][arr][1][lane]) +
            (ps[pp][arr][2][lane] + ps[pp][arr][3][lane]);
      }
      s = msk ? s : -1e30f;
      float mx = s;
      for (int m = 32; m >= 1; m >>= 1) mx = fmaxf(mx, __shfl_xor(mx, m));
      float e = __expf(s - mx);
      float sum = e;
      for (int m = 32; m >= 1; m >>= 1) sum += __shfl_xor(sum, m);
      asw[pp][wv][lane] = e / sum;
    }
  }
  __syncthreads();
  {
    int d = tid;
    const float* qcol = qry + (size_t)b * Q_ * H2_ + d;
    float o00 = 0.f, o01 = 0.f, o02 = 0.f, o03 = 0.f;
    float o10 = 0.f, o11 = 0.f, o12 = 0.f, o13 = 0.f;
#pragma unroll 8
    for (int q2 = 0; q2 < Q_; ++q2) {
      float qv = qcol[(size_t)q2 * H2_];
      o00 += asw[0][0][q2] * qv;
      o01 += asw[0][1][q2] * qv;
      o02 += asw[0][2][q2] * qv;
      o03 += asw[0][3][q2] * qv;
      o10 += asw[1][0][q2] * qv;
      o11 += asw[1][1][q2] * qv;
      o12 += asw[1][2][q2] * qv;
      o13 += asw[1][3][q2] * qv;
    }
    _Float16* arow0 = agg_h + rowp * H10_;
    arow0[d] = (_Float16)pas[rowp * H2_ + d];
    arow0[256 + d] = (_Float16)o00;
    arow0[512 + d] = (_Float16)o01;
    arow0[768 + d] = (_Float16)o02;
    arow0[1024 + d] = (_Float16)o03;
    _Float16* arow1 = agg_h + (rowp + 1) * H10_;
    arow1[d] = (_Float16)pas[(rowp + 1) * H2_ + d];
    arow1[256 + d] = (_Float16)o10;
    arow1[512 + d] = (_Float16)o11;
    arow1[768 + d] = (_Float16)o12;
    arow1[1024 + d] = (_Float16)o13;
  }
}

// ---------------- gi = agg_in @ gWih + gbih (both dirs), f16 MFMA ----------------
__global__ __launch_bounds__(256) void k_gi(
    const _Float16* __restrict__ agg_h, const _Float16* __restrict__ gih_sw,
    const float* __restrict__ gbih_f, const float* __restrict__ gbih_b,
    float* __restrict__ gi_f, float* __restrict__ gi_b) {
  int dir = blockIdx.y;
  const float* gbih = dir ? gbih_b : gbih_f;
  float* gi = dir ? gi_b : gi_f;
  int tid = threadIdx.x;
  int w = tid >> 6, l = tid & 63;
  int p0 = blockIdx.x * 64 + w * 16;
  const _Float16* arow = agg_h + ((size_t)(p0 + (l & 15))) * H10_ + ((l >> 4) << 2);
  const _Float16* bbase = gih_sw + (size_t)dir * 80 * 24 * 64 * 4 + (size_t)l * 4;
  f32x4 acc[24] = {};
  for (int ks = 0; ks < 80; ++ks) {
    half4_t a = *(const half4_t*)(arow + ks * 16);
    const _Float16* bkt = bbase + (size_t)ks * 24 * 64 * 4;
#pragma unroll
    for (int ht = 0; ht < 24; ++ht) {
      half4_t bf = *(const half4_t*)(bkt + (size_t)ht * 64 * 4);
      acc[ht] = __builtin_amdgcn_mfma_f32_16x16x16f16(a, bf, acc[ht], 0, 0, 0);
    }
  }
  int r0 = p0 + ((l >> 4) << 2);
#pragma unroll
  for (int ht = 0; ht < 24; ++ht) {
    int col = ht * 16 + (l & 15);
    float bias = gbih[col];
#pragma unroll
    for (int j = 0; j < 4; ++j)
      gi[((size_t)(r0 + j)) * G_ + col] = acc[ht][j] + bias;
  }
}

// ---------------- GRU scan v7 (revert): 8 waves, K=32 MFMA, 6 indep 2-deep chains ----------------
__global__ __attribute__((amdgpu_waves_per_eu(2, 2))) __launch_bounds__(512) void k_gru(
    const float* __restrict__ gi_f, const float* __restrict__ gi_b,
    const _Float16* __restrict__ whh_sw,
    const float* __restrict__ bhh_f, const float* __restrict__ bhh_b,
    float* __restrict__ agg) {
  int dir = blockIdx.x >> 3;
  int bb = blockIdx.x & 7;
  const float* gi = dir ? gi_b : gi_f;
  const float* bhh = dir ? bhh_b : bhh_f;
  int tid = threadIdx.x;
  int w = tid >> 6, l = tid & 63;
  int j = w * 16 + (l & 15);
  half8_t Bf[3][4];
  {
    const _Float16* wb = whh_sw + (size_t)dir * 4 * 24 * 64 * 8;
#pragma unroll
    for (int g = 0; g < 3; ++g) {
      int ct = g * 8 + w;
#pragma unroll
      for (int ks = 0; ks < 4; ++ks)
        Bf[g][ks] = *(const half8_t*)(wb + (((size_t)(ks * 24 + ct)) * 64 + l) * 8);
    }
  }
  float bhr = bhh[j], bhz = bhh[128 + j], bhn = bhh[256 + j];
  __shared__ __align__(16) _Float16 hsbuf[2][H_];
  if (tid < H_) hsbuf[0][tid] = (_Float16)0.f;
  float hprev = 0.f;
  int p = dir ? (P_ - 1) : 0;
  int dp = dir ? -1 : 1;
  size_t gbase = (size_t)bb * P_;
  float g0r, g0z, g0n, g1r, g1z, g1n;
  {
    size_t r0 = (gbase + p) * G_;
    g0r = gi[r0 + j]; g0z = gi[r0 + 128 + j]; g0n = gi[r0 + 256 + j];
    size_t r1 = (gbase + p + dp) * G_;
    g1r = gi[r1 + j]; g1z = gi[r1 + 128 + j]; g1n = gi[r1 + 256 + j];
  }
  GRUBAR();
  int cur = 0;
  int ao = (l >> 4) << 3;
  for (int t = 0; t < P_; ++t) {
    float g2r = 0.f, g2z = 0.f, g2n = 0.f;
    if (t + 2 < P_) {
      size_t r2 = (gbase + p + 2 * dp) * G_;
      g2r = gi[r2 + j]; g2z = gi[r2 + 128 + j]; g2n = gi[r2 + 256 + j];
    }
    const _Float16* hb = hsbuf[cur];
    half8_t ha[4];
#pragma unroll
    for (int ks = 0; ks < 4; ++ks) ha[ks] = *(const half8_t*)(hb + ks * 32 + ao);
    f32x4 arL = {}, arH = {}, azL = {}, azH = {}, anL = {}, anH = {};
    arL = __builtin_amdgcn_mfma_f32_16x16x32_f16(ha[0], Bf[0][0], arL, 0, 0, 0);
    azL = __builtin_amdgcn_mfma_f32_16x16x32_f16(ha[0], Bf[1][0], azL, 0, 0, 0);
    anL = __builtin_amdgcn_mfma_f32_16x16x32_f16(ha[0], Bf[2][0], anL, 0, 0, 0);
    arH = __builtin_amdgcn_mfma_f32_16x16x32_f16(ha[2], Bf[0][2], arH, 0, 0, 0);
    azH = __builtin_amdgcn_mfma_f32_16x16x32_f16(ha[2], Bf[1][2], azH, 0, 0, 0);
    anH = __builtin_amdgcn_mfma_f32_16x16x32_f16(ha[2], Bf[2][2], anH, 0, 0, 0);
    arL = __builtin_amdgcn_mfma_f32_16x16x32_f16(ha[1], Bf[0][1], arL, 0, 0, 0);
    azL = __builtin_amdgcn_mfma_f32_16x16x32_f16(ha[1], Bf[1][1], azL, 0, 0, 0);
    anL = __builtin_amdgcn_mfma_f32_16x16x32_f16(ha[1], Bf[2][1], anL, 0, 0, 0);
    arH = __builtin_amdgcn_mfma_f32_16x16x32_f16(ha[3], Bf[0][3], arH, 0, 0, 0);
    azH = __builtin_amdgcn_mfma_f32_16x16x32_f16(ha[3], Bf[1][3], azH, 0, 0, 0);
    anH = __builtin_amdgcn_mfma_f32_16x16x32_f16(ha[3], Bf[2][3], anH, 0, 0, 0);
    float arS = arL[0] + arH[0];
    float azS = azL[0] + azH[0];
    float anS = anL[0] + anH[0];
    float r = fast_sigm(g0r + arS + bhr);
    float z = fast_sigm(g0z + azS + bhz);
    float nn = fast_tanh(g0n + r * (anS + bhn));
    float hnew = (1.f - z) * nn + z * hprev;
    hprev = hnew;
    if (l < 16) {
      hsbuf[cur ^ 1][j] = (_Float16)hnew;
      agg[(size_t)(gbase + p) * H2_ + dir * H_ + j] = hnew;
    }
    GRUBAR();
    cur ^= 1;
    g0r = g1r; g0z = g1z; g0n = g1n;
    g1r = g2r; g1z = g2z; g1n = g2n;
    p += dp;
  }
}

// ---------------- sp raw scores v2: 8 p-rows per block ----------------
__global__ __launch_bounds__(128) void k_spscore(
    const float* __restrict__ agg, const float* __restrict__ wp1,
    const float* __restrict__ rqw2, const float* __restrict__ vp,
    float* __restrict__ spraw) {
  int bx = blockIdx.x;
  int b = bx >> 6, p0 = (bx & 63) * 8;
  int h = threadIdx.x;
  const float* ar = agg + ((size_t)b * P_ + p0) * H2_;
  float base = rqw2[b * H_ + h];
  float acc[8];
#pragma unroll
  for (int r = 0; r < 8; ++r) acc[r] = base;
#pragma unroll 4
  for (int d = 0; d < H2_; ++d) {
    float wv = wp1[(size_t)d * H_ + h];
#pragma unroll
    for (int r = 0; r < 8; ++r) acc[r] += ar[(size_t)r * H2_ + d] * wv;
  }
  __shared__ float par[8][2];
  float vph = vp[h];
#pragma unroll
  for (int r = 0; r < 8; ++r) {
    float v = fast_tanh(acc[r]) * vph;
    for (int m = 32; m >= 1; m >>= 1) v += __shfl_xor(v, m);
    if ((h & 63) == 0) par[r][h >> 6] = v;
  }
  __syncthreads();
  if (h < 8) spraw[(size_t)b * P_ + p0 + h] = par[h][0] + par[h][1];
}

// ---------------- final head ----------------
__global__ __launch_bounds__(256) void k_final(
    const float* __restrict__ spraw, const int* __restrict__ pmask,
    const float* __restrict__ agg, const float* __restrict__ predict_w,
    const float* __restrict__ alters, float* __restrict__ out) {
  int b = blockIdx.x;
  int t = threadIdx.x;
  __shared__ float sp[P_];
  __shared__ float red[4];
  __shared__ float rpr[H2_];
  __shared__ float rpl[H_];
  __shared__ float lg[3];
  float s0 = (pmask[b * P_ + t] != 0) ? spraw[b * P_ + t] : -1e30f;
  float s1 = (pmask[b * P_ + 256 + t] != 0) ? spraw[b * P_ + 256 + t] : -1e30f;
  float mx = fmaxf(s0, s1);
  for (int m = 32; m >= 1; m >>= 1) mx = fmaxf(mx, __shfl_xor(mx, m));
  if ((t & 63) == 0) red[t >> 6] = mx;
  __syncthreads();
  mx = fmaxf(fmaxf(red[0], red[1]), fmaxf(red[2], red[3]));
  float e0 = __expf(s0 - mx), e1 = __expf(s1 - mx);
  float ss = e0 + e1;
  for (int m = 32; m >= 1; m >>= 1) ss += __shfl_xor(ss, m);
  __syncthreads();
  if ((t & 63) == 0) red[t >> 6] = ss;
  __syncthreads();
  float tot = red[0] + red[1] + red[2] + red[3];
  float inv = 1.f / tot;
  sp[t] = e0 * inv;
  sp[256 + t] = e1 * inv;
  __syncthreads();
  {
    float acc = 0.f;
    const float* acol = agg + (size_t)b * P_ * H2_ + t;
#pragma unroll 8
    for (int p = 0; p < P_; ++p) acc += sp[p] * acol[(size_t)p * H2_];
    rpr[t] = acc;
  }
  __syncthreads();
  if (t < H_) {
    float acc = 0.f;
#pragma unroll 4
    for (int d = 0; d < H2_; ++d) acc += rpr[d] * predict_w[(size_t)d * H_ + t];
    rpl[t] = (acc > 0.f) ? acc : 0.01f * acc;
  }
  __syncthreads();
  if (t < 3) {
    float acc = 0.f;
    const float* al = alters + ((size_t)(b * 3 + t)) * H_;
    for (int h = 0; h < H_; ++h) acc += al[h] * rpl[h];
    lg[t] = acc;
  }
  __syncthreads();
  if (t == 0) {
    float m3 = fmaxf(lg[0], fmaxf(lg[1], lg[2]));
    float x0 = __expf(lg[0] - m3), x1 = __expf(lg[1] - m3), x2 = __expf(lg[2] - m3);
    float is = 1.f / (x0 + x1 + x2);
    out[b * 3 + 0] = x0 * is;
    out[b * 3 + 1] = x1 * is;
    out[b * 3 + 2] = x2 * is;
  }
}

extern "C" void kernel_launch(void* const* d_in, const int* in_sizes, int n_in,
                              void* d_out, int out_size, void* d_ws, size_t ws_size,
                              hipStream_t stream) {
  (void)in_sizes; (void)n_in; (void)out_size; (void)ws_size;
  const float* pas = (const float*)d_in[0];
  const float* qry = (const float*)d_in[1];
  const float* alt1 = (const float*)d_in[2];
  const float* alt2 = (const float*)d_in[3];
  const float* alt3 = (const float*)d_in[4];
  const float* a_att_w = (const float*)d_in[5];
  const float* Wc1 = (const float*)d_in[6];
  const float* Wc2 = (const float*)d_in[7];
  const float* vc = (const float*)d_in[8];
  const float* Wb = (const float*)d_in[9];
  const float* Wd = (const float*)d_in[10];
  const float* vd = (const float*)d_in[11];
  const float* Wm = (const float*)d_in[12];
  const float* vm = (const float*)d_in[13];
  const float* wq = (const float*)d_in[14];
  const float* vq = (const float*)d_in[15];
  const float* wp1 = (const float*)d_in[16];
  const float* wp2 = (const float*)d_in[17];
  const float* vp = (const float*)d_in[18];
  const float* predict_w = (const float*)d_in[19];
  const float* gWih_f = (const float*)d_in[20];
  const float* gWhh_f = (const float*)d_in[21];
  const float* gbih_f = (const float*)d_in[22];
  const float* gbhh_f = (const float*)d_in[23];
  const float* gWih_b = (const float*)d_in[24];
  const float* gWhh_b = (const float*)d_in[25];
  const float* gbih_b = (const float*)d_in[26];
  const float* gbhh_b = (const float*)d_in[27];
  const int* pmask = (const int*)d_in[28];
  const int* qmask = (const int*)d_in[29];
  const int* m1 = (const int*)d_in[30];
  const int* m2 = (const int*)d_in[31];
  const int* m3 = (const int*)d_in[32];
  float* out = (float*)d_out;

  char* ws = (char*)d_ws;
  size_t off = 0;
  auto alloc_f = [&](size_t n) {
    float* ptr = (float*)(ws + off);
    off += n * 4;
    off = (off + 255) & ~(size_t)255;
    return ptr;
  };
  float* alters = alloc_f((size_t)B_ * 3 * H_);
  float* p1 = alloc_f((size_t)B_ * P_ * H_);
  float* pmp = alloc_f((size_t)B_ * P_ * H_);
  float* pasWb = alloc_f((size_t)B_ * P_ * H2_);
  float* scd = alloc_f((size_t)B_ * P_ * Q_);
  float* gi_f = alloc_f((size_t)B_ * P_ * G_);
  float* gi_b = alloc_f((size_t)B_ * P_ * G_);
  float* agg = alloc_f((size_t)B_ * P_ * H2_);
  float* sjraw = alloc_f((size_t)B_ * Q_);
  float* rqw2 = alloc_f((size_t)B_ * H_);
  float* spraw = alloc_f((size_t)B_ * P_);
  float* q1T = alloc_f((size_t)B_ * H_ * Q_);
  float* pmqT = alloc_f((size_t)B_ * H_ * Q_);
  float* qryT = alloc_f((size_t)B_ * H2_ * Q_);
  auto alloc_h = [&](size_t n) {
    _Float16* ptr = (_Float16*)(ws + off);
    off += n * 2;
    off = (off + 255) & ~(size_t)255;
    return ptr;
  };
  _Float16* wd_sw = alloc_h((size_t)16 * 8 * 64 * 4);
  _Float16* gih_sw = alloc_h((size_t)2 * 80 * 24 * 64 * 4);
  _Float16* agg_h = alloc_h((size_t)B_ * P_ * H10_);
  _Float16* whh_sw = alloc_h((size_t)2 * 4 * 24 * 64 * 8);
  _Float16* pas_h = alloc_h((size_t)B_ * P_ * H2_);
  _Float16* wpc_sw = alloc_h((size_t)16 * 32 * 64 * 4);

  k_pre<<<NB_PRE, 256, 0, stream>>>(
      alt1, alt2, alt3, m1, m2, m3, a_att_w, alters,
      Wd, wd_sw, gWih_f, gWih_b, gih_sw, gWhh_f, gWhh_b, whh_sw,
      pas, qry, pas_h, Wc1, Wm, Wb, wpc_sw, qryT, Wc2, q1T, pmqT, wq, vq, sjraw);
  k_scd_rq<<<512 + B_ + 128, 256, 0, stream>>>(
      qry, wd_sw, vd, scd, sjraw, qmask, wp2, rqw2,
      pas_h, wpc_sw, p1, pmp, pasWb);
  k_attend<<<B_ * P_ / 2, 256, 0, stream>>>(
      pas, qry, p1, pmp, q1T, pmqT, qryT, pasWb, scd, vc, vm, qmask, agg_h);
  k_gi<<<dim3(64, 2), 256, 0, stream>>>(agg_h, gih_sw, gbih_f, gbih_b, gi_f, gi_b);
  k_gru<<<16, 512, 0, stream>>>(gi_f, gi_b, whh_sw, gbhh_f, gbhh_b, agg);
  k_spscore<<<B_ * P_ / 8, 128, 0, stream>>>(agg, wp1, rqw2, vp, spraw);
  k_final<<<B_, 256, 0, stream>>>(spraw, pmask, agg, predict_w, alters, out);
}